// Round 5
// baseline (136.896 us; speedup 1.0000x reference)
//
#include <hip/hip_runtime.h>
#include <hip/hip_bf16.h>

#define NBAGS 16384
#define OUT_STRIDE 288

// LLVM SchedGroupMask
#define SGB_VALU 0x2
#define SGB_VMEM_READ 0x20

struct Ptrs {
    const float* W[4];
    const int* ids[4];
    const int* lens[4];
    int* starts[4];
    float* out;
};

// Brute-force chunked exclusive scan: grid = 4 tables x 256 chunks.
__global__ void __launch_bounds__(256) scan_kernel(Ptrs p) {
    const int t = blockIdx.x >> 8;
    const int c = blockIdx.x & 255;
    const int* __restrict__ lens = p.lens[t];
    int* __restrict__ starts = p.starts[t];
    const int tid = threadIdx.x;
    const int P = c * 64;

    __shared__ int red[256];
    int s = 0;
    for (int k = tid; k < P; k += 256) s += lens[k];
    red[tid] = s;
    __syncthreads();
    for (int off = 128; off > 0; off >>= 1) {
        if (tid < off) red[tid] += red[tid + off];
        __syncthreads();
    }
    const int prefix = red[0];

    if (tid < 64) {
        const int v = lens[P + tid];
        int inc = v;
#pragma unroll
        for (int off = 1; off < 64; off <<= 1) {
            int u = __shfl_up(inc, off, 64);
            if (tid >= off) inc += u;
        }
        starts[P + tid] = prefix + inc - v;
    }
}

// One unit = 8 bags, 256 threads; G groups of TPB=D/4 lanes per bag.
// U=8 row-gathers in flight, only 4 accumulators (acc[u&3]) to leave VGPRs
// for the in-flight row buffers; sched_group_barrier pins the emitted order
// to {addr VALU, 8 clustered row-gathers, 8 id loads, FMAs} so the wave has
// all 16 VMEM ops outstanding before the first vmcnt wait.
template <int D, int G, int U>
__device__ __forceinline__ void pool_unit(
    const float* __restrict__ W, const int* __restrict__ ids,
    const int* __restrict__ starts, const int* __restrict__ lens,
    float* __restrict__ out, int col_off, int chunk, float4* sm)
{
    constexpr int TPB = D / 4;             // lanes per group
    constexpr int SLOTS = 256 / (TPB * G); // bags per block (8 everywhere)
    constexpr unsigned RB = (unsigned)(D * 4);  // row bytes
    const int tid = threadIdx.x;
    const int slot = tid / (TPB * G);
    const int g = (tid / TPB) % G;
    const int lane = tid % TPB;
    const int bag = chunk * SLOTS + slot;
    const int s = starts[bag];
    const int n = lens[bag];
    const char* __restrict__ Wb = reinterpret_cast<const char*>(W);
    const unsigned lane16 = (unsigned)(lane * 16);

    float4 acc[4];
#pragma unroll
    for (int u = 0; u < 4; ++u) acc[u] = make_float4(0.f, 0.f, 0.f, 0.f);

    int j0 = g;
    int idxA[U];
#pragma unroll
    for (int u = 0; u < U; ++u) {
        const int jj = j0 + u * G;
        idxA[u] = (jj < n) ? ids[s + jj] : -1;
    }

    while (true) {
        // issue U row gathers (always load; mask the add)
        float4 r[U];
#pragma unroll
        for (int u = 0; u < U; ++u) {
            const int id = idxA[u];
            const unsigned off = (unsigned)(id < 0 ? 0 : id) * RB + lane16;
            r[u] = *reinterpret_cast<const float4*>(Wb + off);
        }
        // prefetch next batch ids while gathers are in flight
        const int j1 = j0 + U * G;
        int idxB[U];
#pragma unroll
        for (int u = 0; u < U; ++u) {
            const int jj = j1 + u * G;
            idxB[u] = (jj < n) ? ids[s + jj] : -1;
        }
        // accumulate into 4 accs (frees 16 VGPRs vs acc[U])
#pragma unroll
        for (int u = 0; u < U; ++u) {
            const float m = (idxA[u] >= 0) ? 1.f : 0.f;
            acc[u & 3].x = fmaf(m, r[u].x, acc[u & 3].x);
            acc[u & 3].y = fmaf(m, r[u].y, acc[u & 3].y);
            acc[u & 3].z = fmaf(m, r[u].z, acc[u & 3].z);
            acc[u & 3].w = fmaf(m, r[u].w, acc[u & 3].w);
        }

        // pin schedule: addr VALU, clustered row gathers, id loads, FMAs
        __builtin_amdgcn_sched_group_barrier(SGB_VALU, 24, 0);
        __builtin_amdgcn_sched_group_barrier(SGB_VMEM_READ, U, 0);
        __builtin_amdgcn_sched_group_barrier(SGB_VMEM_READ, U, 0);
        __builtin_amdgcn_sched_group_barrier(SGB_VALU, 64, 0);

        j0 = j1;
        if (j0 >= n) break;
#pragma unroll
        for (int u = 0; u < U; ++u) idxA[u] = idxB[u];
    }

    acc[0].x += acc[1].x + acc[2].x + acc[3].x;
    acc[0].y += acc[1].y + acc[2].y + acc[3].y;
    acc[0].z += acc[1].z + acc[2].z + acc[3].z;
    acc[0].w += acc[1].w + acc[2].w + acc[3].w;

    if constexpr (G == 1) {
        float4* o = reinterpret_cast<float4*>(out + (size_t)bag * OUT_STRIDE + col_off) + lane;
        *o = acc[0];
    } else {
        sm[tid] = acc[0];
        __syncthreads();
        if (g == 0) {
#pragma unroll
            for (int h = 1; h < G; ++h) {
                const float4 v = sm[tid + h * TPB];
                acc[0].x += v.x; acc[0].y += v.y; acc[0].z += v.z; acc[0].w += v.w;
            }
            float4* o = reinterpret_cast<float4*>(out + (size_t)bag * OUT_STRIDE + col_off) + lane;
            *o = acc[0];
        }
    }
}

// grid = 8192: unit u -> table u&3, chunk u>>2; uniform work per block.
__global__ void __launch_bounds__(256) pool_fused(Ptrs p) {
    __shared__ float4 sm[256];
    const int u = blockIdx.x;
    const int chunk = u >> 2;
    switch (u & 3) {
    case 0: pool_unit<64, 2, 8>(p.W[0], p.ids[0], p.starts[0], p.lens[0], p.out, 0,   chunk, sm); break;
    case 1: pool_unit<128, 1, 8>(p.W[1], p.ids[1], p.starts[1], p.lens[1], p.out, 64,  chunk, sm); break;
    case 2: pool_unit<32, 4, 8>(p.W[2], p.ids[2], p.starts[2], p.lens[2], p.out, 192, chunk, sm); break;
    default: pool_unit<64, 2, 8>(p.W[3], p.ids[3], p.starts[3], p.lens[3], p.out, 224, chunk, sm); break;
    }
}

extern "C" void kernel_launch(void* const* d_in, const int* in_sizes, int n_in,
                              void* d_out, int out_size, void* d_ws, size_t ws_size,
                              hipStream_t stream) {
    Ptrs p;
    for (int t = 0; t < 4; ++t) {
        p.W[t]    = (const float*)d_in[3 * t + 0];
        p.ids[t]  = (const int*)d_in[3 * t + 1];
        p.lens[t] = (const int*)d_in[3 * t + 2];
        p.starts[t] = (int*)d_ws + t * NBAGS;
    }
    p.out = (float*)d_out;

    scan_kernel<<<1024, 256, 0, stream>>>(p);
    pool_fused<<<NBAGS / 8 * 4, 256, 0, stream>>>(p);
}